// Round 1
// baseline (481.308 us; speedup 1.0000x reference)
//
#include <hip/hip_runtime.h>
#include <hip/hip_bf16.h>

typedef __attribute__((ext_vector_type(8))) short bf16x8;
typedef __attribute__((ext_vector_type(4))) float f32x4;

#define MFMA __builtin_amdgcn_mfma_f32_16x16x32_bf16

__device__ __forceinline__ unsigned short f2bf(float f) {
    unsigned int u = __builtin_bit_cast(unsigned int, f);
    u += 0x7fffu + ((u >> 16) & 1u);
    return (unsigned short)(u >> 16);
}
__device__ __forceinline__ float bf2f(unsigned short h) {
    unsigned int u = ((unsigned int)h) << 16;
    return __builtin_bit_cast(float, u);
}

// ---------------------------------------------------------------------------
// Weight prep: W' [col][d] (bf16 hi/lo split), col-major-friendly for B-frags.
// hpd=1: W is [H=8][D=512][P=64], col = h*64+p.  hpd=0: W is [512][512], col = out col.
// ---------------------------------------------------------------------------
__global__ __launch_bounds__(256) void prep_w(const float* __restrict__ W,
                                              unsigned short* __restrict__ hi,
                                              unsigned short* __restrict__ lo,
                                              float scale, int hpd) {
    int tid = blockIdx.x * 256 + threadIdx.x;   // 512*512 total
    int col = tid >> 9, d = tid & 511;
    float x;
    if (hpd) x = W[(size_t)(col >> 6) * (512 * 64) + (size_t)d * 64 + (col & 63)];
    else     x = W[(size_t)d * 512 + col];
    x *= scale;
    unsigned short h = f2bf(x);
    hi[tid] = h;
    if (lo) lo[tid] = f2bf(x - bf2f(h));
}

// ---------------------------------------------------------------------------
// Projection GEMM: Y[8192][512] = X[8192][512] * W'[512][512]  (split 3-term)
// mode 0: write hi/lo bf16 at [b*8+h][s][p]   (q, k)
// mode 1: write single bf16 TRANSPOSED at [(b*8+h)*64+p][t]  (v)
// ---------------------------------------------------------------------------
__global__ __launch_bounds__(256) void proj_kernel(
    const float* __restrict__ X,
    const unsigned short* __restrict__ Wh,
    const unsigned short* __restrict__ Wl,
    unsigned short* __restrict__ Oh,
    unsigned short* __restrict__ Ol,
    int mode)
{
    const int lane = threadIdx.x & 63;
    const int wave = threadIdx.x >> 6;
    const int lr = lane & 15, lg = lane >> 4;
    const int rb = blockIdx.x >> 3;
    const int cb = blockIdx.x & 7;
    const int row0 = rb * 128 + wave * 32;
    const int col0 = cb * 64;

    f32x4 acc[2][4];
#pragma unroll
    for (int m = 0; m < 2; ++m)
#pragma unroll
        for (int n = 0; n < 4; ++n) acc[m][n] = {0.f, 0.f, 0.f, 0.f};

    for (int ks = 0; ks < 16; ++ks) {
        const int d0 = ks * 32 + lg * 8;
        bf16x8 ah[2], al[2];
#pragma unroll
        for (int m = 0; m < 2; ++m) {
            const float* px = X + (size_t)(row0 + m * 16 + lr) * 512 + d0;
            f32x4 x0 = *reinterpret_cast<const f32x4*>(px);
            f32x4 x1 = *reinterpret_cast<const f32x4*>(px + 4);
#pragma unroll
            for (int j = 0; j < 4; ++j) {
                unsigned short h0 = f2bf(x0[j]);
                unsigned short h1 = f2bf(x1[j]);
                ah[m][j]     = (short)h0;
                ah[m][j + 4] = (short)h1;
                al[m][j]     = (short)f2bf(x0[j] - bf2f(h0));
                al[m][j + 4] = (short)f2bf(x1[j] - bf2f(h1));
            }
        }
#pragma unroll
        for (int n = 0; n < 4; ++n) {
            size_t woff = (size_t)(col0 + n * 16 + lr) * 512 + d0;
            bf16x8 bh = *reinterpret_cast<const bf16x8*>(Wh + woff);
            bf16x8 bl = *reinterpret_cast<const bf16x8*>(Wl + woff);
#pragma unroll
            for (int m = 0; m < 2; ++m) {
                f32x4 a = acc[m][n];
                a = MFMA(ah[m], bh, a, 0, 0, 0);
                a = MFMA(al[m], bh, a, 0, 0, 0);
                a = MFMA(ah[m], bl, a, 0, 0, 0);
                acc[m][n] = a;
            }
        }
    }

#pragma unroll
    for (int m = 0; m < 2; ++m)
#pragma unroll
        for (int n = 0; n < 4; ++n)
#pragma unroll
            for (int r = 0; r < 4; ++r) {
                int grow = row0 + m * 16 + lg * 4 + r;
                int col  = col0 + n * 16 + lr;
                int b = grow >> 11, s = grow & 2047;
                int h = col >> 6,  p = col & 63;
                float v = acc[m][n][r];
                if (mode == 0) {
                    size_t o = ((size_t)(b * 8 + h) * 2048 + s) * 64 + p;
                    unsigned short hv = f2bf(v);
                    Oh[o] = hv;
                    Ol[o] = f2bf(v - bf2f(hv));
                } else {
                    size_t o = ((size_t)(b * 8 + h) * 64 + p) * 2048 + s;
                    Oh[o] = f2bf(v);
                }
            }
}

// ---------------------------------------------------------------------------
// Flash attention: per block one (b,h) and a 128-row q tile. 4 waves, each
// owns 32 q rows. K tiles of 64. Scores via 3-term split MFMA. Online softmax
// wave-parallel. P staged through per-wave-private LDS (no barriers).
// ---------------------------------------------------------------------------
__global__ __launch_bounds__(256) void attn_kernel(
    const unsigned short* __restrict__ Qh, const unsigned short* __restrict__ Ql,
    const unsigned short* __restrict__ Kh, const unsigned short* __restrict__ Kl,
    const unsigned short* __restrict__ VT,   // [32*64][2048]
    unsigned short* __restrict__ Att)        // [4][2048][512]
{
    __shared__ __align__(16) unsigned char plds[4 * 32 * 144];
    const int lane = threadIdx.x & 63;
    const int wave = threadIdx.x >> 6;
    const int lr = lane & 15, lg = lane >> 4;
    const int bh = blockIdx.x >> 4;
    const int qt = blockIdx.x & 15;
    const int q0 = qt * 128 + wave * 32;
    unsigned char* pl = plds + wave * (32 * 144);

    // Q fragments in registers (hi + lo), loaded once
    bf16x8 qfh[2][2], qfl[2][2];
#pragma unroll
    for (int m = 0; m < 2; ++m)
#pragma unroll
        for (int ks = 0; ks < 2; ++ks) {
            size_t off = ((size_t)bh * 2048 + q0 + m * 16 + lr) * 64 + ks * 32 + lg * 8;
            qfh[m][ks] = *reinterpret_cast<const bf16x8*>(Qh + off);
            qfl[m][ks] = *reinterpret_cast<const bf16x8*>(Ql + off);
        }

    f32x4 oacc[2][4];
    f32x4 mrun[2], lrun[2];
#pragma unroll
    for (int m = 0; m < 2; ++m) {
        mrun[m] = {-1e30f, -1e30f, -1e30f, -1e30f};
        lrun[m] = {0.f, 0.f, 0.f, 0.f};
#pragma unroll
        for (int n = 0; n < 4; ++n) oacc[m][n] = {0.f, 0.f, 0.f, 0.f};
    }

    const float LOG2E = 1.4426950408889634f;

    for (int kt = 0; kt < 32; ++kt) {
        // ---- scores: S = (Q/8) K^T, split 3-term ----
        f32x4 sc[2][4];
#pragma unroll
        for (int n = 0; n < 4; ++n) {
            size_t koff = ((size_t)bh * 2048 + kt * 64 + n * 16 + lr) * 64 + lg * 8;
            bf16x8 kh0 = *reinterpret_cast<const bf16x8*>(Kh + koff);
            bf16x8 kh1 = *reinterpret_cast<const bf16x8*>(Kh + koff + 32);
            bf16x8 kl0 = *reinterpret_cast<const bf16x8*>(Kl + koff);
            bf16x8 kl1 = *reinterpret_cast<const bf16x8*>(Kl + koff + 32);
#pragma unroll
            for (int m = 0; m < 2; ++m) {
                f32x4 a = {0.f, 0.f, 0.f, 0.f};
                a = MFMA(qfh[m][0], kh0, a, 0, 0, 0);
                a = MFMA(qfh[m][1], kh1, a, 0, 0, 0);
                a = MFMA(qfl[m][0], kh0, a, 0, 0, 0);
                a = MFMA(qfl[m][1], kh1, a, 0, 0, 0);
                a = MFMA(qfh[m][0], kl0, a, 0, 0, 0);
                a = MFMA(qfh[m][1], kl1, a, 0, 0, 0);
                sc[m][n] = a;
            }
        }

        // ---- online softmax (rows live on (lg, r); cols across the 16 lr lanes) ----
#pragma unroll
        for (int m = 0; m < 2; ++m) {
            f32x4 tmax;
#pragma unroll
            for (int r = 0; r < 4; ++r)
                tmax[r] = fmaxf(fmaxf(sc[m][0][r], sc[m][1][r]),
                                fmaxf(sc[m][2][r], sc[m][3][r]));
#pragma unroll
            for (int msk = 1; msk < 16; msk <<= 1)
#pragma unroll
                for (int r = 0; r < 4; ++r)
                    tmax[r] = fmaxf(tmax[r], __shfl_xor(tmax[r], msk));

            f32x4 mnew, scale, rsum;
#pragma unroll
            for (int r = 0; r < 4; ++r) {
                mnew[r]  = fmaxf(mrun[m][r], tmax[r]);
                scale[r] = exp2f((mrun[m][r] - mnew[r]) * LOG2E);
                rsum[r]  = 0.f;
            }
#pragma unroll
            for (int n = 0; n < 4; ++n)
#pragma unroll
                for (int r = 0; r < 4; ++r) {
                    float p = exp2f((sc[m][n][r] - mnew[r]) * LOG2E);
                    sc[m][n][r] = p;
                    rsum[r] += p;
                }
#pragma unroll
            for (int msk = 1; msk < 16; msk <<= 1)
#pragma unroll
                for (int r = 0; r < 4; ++r)
                    rsum[r] += __shfl_xor(rsum[r], msk);
#pragma unroll
            for (int r = 0; r < 4; ++r)
                lrun[m][r] = lrun[m][r] * scale[r] + rsum[r];
            mrun[m] = mnew;
#pragma unroll
            for (int n = 0; n < 4; ++n)
#pragma unroll
                for (int r = 0; r < 4; ++r)
                    oacc[m][n][r] *= scale[r];
        }

        // ---- stage P into per-wave LDS (XOR-swizzled, stride 144B) ----
#pragma unroll
        for (int m = 0; m < 2; ++m)
#pragma unroll
            for (int n = 0; n < 4; ++n)
#pragma unroll
                for (int r = 0; r < 4; ++r) {
                    int s = m * 16 + lg * 4 + r;
                    int t = n * 16 + lr;
                    int addr = s * 144 + ((2 * t) ^ ((s & 7) << 4));
                    *reinterpret_cast<unsigned short*>(pl + addr) = f2bf(sc[m][n][r]);
                }

        // ---- P A-frags from LDS ----
        bf16x8 pa[2][2];
#pragma unroll
        for (int m = 0; m < 2; ++m)
#pragma unroll
            for (int ks = 0; ks < 2; ++ks) {
                int s = m * 16 + lr;
                int t0 = ks * 32 + lg * 8;
                int addr = s * 144 + ((2 * t0) ^ ((s & 7) << 4));
                pa[m][ks] = *reinterpret_cast<const bf16x8*>(pl + addr);
            }

        // ---- PV ----
#pragma unroll
        for (int n = 0; n < 4; ++n) {
            size_t voff = ((size_t)bh * 64 + n * 16 + lr) * 2048 + kt * 64 + lg * 8;
            bf16x8 vb0 = *reinterpret_cast<const bf16x8*>(VT + voff);
            bf16x8 vb1 = *reinterpret_cast<const bf16x8*>(VT + voff + 32);
#pragma unroll
            for (int m = 0; m < 2; ++m) {
                f32x4 a = oacc[m][n];
                a = MFMA(pa[m][0], vb0, a, 0, 0, 0);
                a = MFMA(pa[m][1], vb1, a, 0, 0, 0);
                oacc[m][n] = a;
            }
        }
    }

    // ---- epilogue: normalize, write attn out bf16 [b][s][h*64+p] ----
    const int b = bh >> 3, h = bh & 7;
#pragma unroll
    for (int m = 0; m < 2; ++m) {
        f32x4 inv;
#pragma unroll
        for (int r = 0; r < 4; ++r) inv[r] = 1.0f / lrun[m][r];
#pragma unroll
        for (int n = 0; n < 4; ++n)
#pragma unroll
            for (int r = 0; r < 4; ++r) {
                int s = q0 + m * 16 + lg * 4 + r;
                int p = n * 16 + lr;
                Att[((size_t)b * 2048 + s) * 512 + h * 64 + p] =
                    f2bf(oacc[m][n][r] * inv[r]);
            }
    }
}

// ---------------------------------------------------------------------------
// Output projection: Out[8192][512] = Att[8192][512] * Wo  (single bf16)
// ---------------------------------------------------------------------------
__global__ __launch_bounds__(256) void outproj_kernel(
    const unsigned short* __restrict__ A,
    const unsigned short* __restrict__ WT,   // [512 col][512 k]
    float* __restrict__ Out)
{
    const int lane = threadIdx.x & 63;
    const int wave = threadIdx.x >> 6;
    const int lr = lane & 15, lg = lane >> 4;
    const int rb = blockIdx.x >> 3;
    const int cb = blockIdx.x & 7;
    const int row0 = rb * 128 + wave * 32;
    const int col0 = cb * 64;

    f32x4 acc[2][4];
#pragma unroll
    for (int m = 0; m < 2; ++m)
#pragma unroll
        for (int n = 0; n < 4; ++n) acc[m][n] = {0.f, 0.f, 0.f, 0.f};

    for (int ks = 0; ks < 16; ++ks) {
        const int k0 = ks * 32 + lg * 8;
        bf16x8 af[2];
#pragma unroll
        for (int m = 0; m < 2; ++m)
            af[m] = *reinterpret_cast<const bf16x8*>(A + (size_t)(row0 + m * 16 + lr) * 512 + k0);
#pragma unroll
        for (int n = 0; n < 4; ++n) {
            bf16x8 bf = *reinterpret_cast<const bf16x8*>(WT + (size_t)(col0 + n * 16 + lr) * 512 + k0);
#pragma unroll
            for (int m = 0; m < 2; ++m)
                acc[m][n] = MFMA(af[m], bf, acc[m][n], 0, 0, 0);
        }
    }

#pragma unroll
    for (int m = 0; m < 2; ++m)
#pragma unroll
        for (int n = 0; n < 4; ++n)
#pragma unroll
            for (int r = 0; r < 4; ++r)
                Out[(size_t)(row0 + m * 16 + lg * 4 + r) * 512 + col0 + n * 16 + lr] =
                    acc[m][n][r];
}

// ---------------------------------------------------------------------------
extern "C" void kernel_launch(void* const* d_in, const int* in_sizes, int n_in,
                              void* d_out, int out_size, void* d_ws, size_t ws_size,
                              hipStream_t stream) {
    (void)in_sizes; (void)n_in; (void)out_size; (void)ws_size;
    const float* q  = (const float*)d_in[0];
    const float* k  = (const float*)d_in[1];
    const float* v  = (const float*)d_in[2];
    const float* Wq = (const float*)d_in[3];
    const float* Wk = (const float*)d_in[4];
    const float* Wv = (const float*)d_in[5];
    const float* Wo = (const float*)d_in[6];
    float* out = (float*)d_out;

    size_t off = 0;
    auto take = [&](size_t bytes) -> void* {
        void* p = (char*)d_ws + off;
        off += (bytes + 255) & ~(size_t)255;
        return p;
    };
    const size_t WSZ = 512 * 512 * sizeof(unsigned short);       // 512 KB
    const size_t BSZ = (size_t)32 * 2048 * 64 * sizeof(unsigned short); // 8 MB

    unsigned short* WqTh = (unsigned short*)take(WSZ);
    unsigned short* WqTl = (unsigned short*)take(WSZ);
    unsigned short* WkTh = (unsigned short*)take(WSZ);
    unsigned short* WkTl = (unsigned short*)take(WSZ);
    unsigned short* WvTh = (unsigned short*)take(WSZ);
    unsigned short* WvTl = (unsigned short*)take(WSZ);
    unsigned short* WoT  = (unsigned short*)take(WSZ);
    unsigned short* Qh   = (unsigned short*)take(BSZ);
    unsigned short* Ql   = (unsigned short*)take(BSZ);
    unsigned short* Kh   = (unsigned short*)take(BSZ);
    unsigned short* Kl   = (unsigned short*)take(BSZ);
    unsigned short* VT   = (unsigned short*)take(BSZ);
    unsigned short* Att  = (unsigned short*)take(BSZ);

    // weight prep (1/sqrt(P)=0.125 folded into Wq)
    prep_w<<<1024, 256, 0, stream>>>(Wq, WqTh, WqTl, 0.125f, 1);
    prep_w<<<1024, 256, 0, stream>>>(Wk, WkTh, WkTl, 1.0f, 1);
    prep_w<<<1024, 256, 0, stream>>>(Wv, WvTh, WvTl, 1.0f, 1);
    prep_w<<<1024, 256, 0, stream>>>(Wo, WoT, nullptr, 1.0f, 0);

    // projections
    proj_kernel<<<512, 256, 0, stream>>>(q, WqTh, WqTl, Qh, Ql, 0);
    proj_kernel<<<512, 256, 0, stream>>>(k, WkTh, WkTl, Kh, Kl, 0);
    proj_kernel<<<512, 256, 0, stream>>>(v, WvTh, WvTl, VT, nullptr, 1);

    // flash attention
    attn_kernel<<<512, 256, 0, stream>>>(Qh, Ql, Kh, Kl, VT, Att);

    // output projection
    outproj_kernel<<<512, 256, 0, stream>>>(Att, WoT, out);
}